// Round 13
// baseline (158.078 us; speedup 1.0000x reference)
//
#include <hip/hip_runtime.h>
#include <hip/hip_bf16.h>

typedef _Float16 h2_t  __attribute__((ext_vector_type(2)));
typedef _Float16 f16x8 __attribute__((ext_vector_type(8)));
typedef float    f32x4 __attribute__((ext_vector_type(4)));

__device__ __forceinline__ float fdot2(h2_t a, h2_t b, float c) {
#if __has_builtin(__builtin_amdgcn_fdot2)
    return __builtin_amdgcn_fdot2(a, b, c, false);
#else
    return c + (float)a.x * (float)b.x + (float)a.y * (float)b.y;
#endif
}

__device__ __forceinline__ unsigned pack2(float lo, float hi) {
    union { h2_t h; unsigned u; } cv;
    cv.h.x = (_Float16)lo; cv.h.y = (_Float16)hi;
    return cv.u;
}

// ---------------------------------------------------------------------------
// Prep (merged): bid<9 -> w2 MFMA B-frags; bid>=9 -> whT transpose to f16.
// ---------------------------------------------------------------------------
__global__ __launch_bounds__(256) void k_prep(
    const float* __restrict__ w2, f16x8* __restrict__ w2f,
    const float* __restrict__ wh, _Float16* __restrict__ whT)
{
    int bid = blockIdx.x;
    if (bid < 9) {
        int idx = bid * 256 + threadIdx.x;      // 9*4*64 = 2304
        int lane = idx & 63;
        int nt   = (idx >> 6) & 3;
        int tap  = idx >> 8;
        int oc = nt * 16 + (lane & 15);
        int c0 = (lane >> 4) * 8;
        f16x8 v;
#pragma unroll
        for (int j = 0; j < 8; ++j)
            v[j] = (_Float16)w2[(tap * 32 + c0 + j) * 64 + oc];
        w2f[idx] = v;
    } else {
        int c = bid - 9;                        // 0..767
        int k = threadIdx.x;                    // 0..255
        whT[c * 256 + k] = (_Float16)wh[k * 768 + c];
    }
}

// ---------------------------------------------------------------------------
// Fused conv1(VALU) + conv2(MFMA) + global-average-pool.  1 block = 1 frame.
// ---------------------------------------------------------------------------
__global__ __launch_bounds__(512, 4) void k_conv(
    const float* __restrict__ x,    // [512][64][64][5]
    const float* __restrict__ w1,   // [3][3][5][32]
    const float* __restrict__ b1,   // [32]
    const f16x8* __restrict__ w2f,  // [9][4][64] B-frags
    const float* __restrict__ b2,   // [64]
    float* __restrict__ pooled)     // [512][64]
{
    __shared__ _Float16 c1s[32 * 33 * 32];   // [ih][iw(+pad)][c] 67.6 KB
    __shared__ float pl[8 * 64];

    const int n = blockIdx.x;
    const int tid = threadIdx.x;
    const int lane = tid & 63, wv = tid >> 6;

    {   // zero the iw==32 pad column
        int r = tid >> 4, d = tid & 15;
        ((unsigned*)c1s)[(r * 33 + 32) * 16 + d] = 0u;
    }

    const float* xf = x + (size_t)n * 20480;

    for (int pp = 0; pp < 2; ++pp) {
        int p = tid + pp * 512;
        int oh = p >> 5, ow = p & 31;
        float acc[32];
#pragma unroll
        for (int oc = 0; oc < 32; ++oc) acc[oc] = b1[oc];
#pragma unroll
        for (int ky = 0; ky < 3; ++ky) {
            int ih = 2 * oh + ky;
            if (ih < 64) {
                const float* rb = xf + (ih * 64 + 2 * ow) * 5;
                float xv[15];
                const float2* rb2 = (const float2*)rb;
#pragma unroll
                for (int q = 0; q < 5; ++q) {
                    float2 v = rb2[q];
                    xv[2 * q] = v.x; xv[2 * q + 1] = v.y;
                }
                if (ow < 31) {
                    float2 v5 = rb2[5], v6 = rb2[6];
                    xv[10] = v5.x; xv[11] = v5.y;
                    xv[12] = v6.x; xv[13] = v6.y;
                    xv[14] = rb[14];
                } else {
                    xv[10] = xv[11] = xv[12] = xv[13] = xv[14] = 0.f;
                }
#pragma unroll
                for (int q = 0; q < 15; ++q) {
                    float v = xv[q];
                    const float* wp = w1 + (ky * 15 + q) * 32;
#pragma unroll
                    for (int oc = 0; oc < 32; ++oc)
                        acc[oc] = fmaf(v, wp[oc], acc[oc]);
                }
            }
        }
        unsigned* dst = (unsigned*)&c1s[(oh * 33 + ow) * 32];
#pragma unroll
        for (int j = 0; j < 16; ++j)
            dst[j] = pack2(fmaxf(acc[2 * j], 0.f), fmaxf(acc[2 * j + 1], 0.f));
    }
    __syncthreads();

    // conv2 as implicit GEMM via MFMA: M=256 px, N=64 oc, K=9x32
    f32x4 acc2[2][4];
#pragma unroll
    for (int mt = 0; mt < 2; ++mt)
#pragma unroll
        for (int nt = 0; nt < 4; ++nt) acc2[mt][nt] = f32x4{0.f, 0.f, 0.f, 0.f};

    const int owl = lane & 15;
    const int cb = (lane >> 4) * 8;
#pragma unroll
    for (int tap = 0; tap < 9; ++tap) {
        const int ky = tap / 3, kx = tap % 3;
        f16x8 bf[4];
#pragma unroll
        for (int nt = 0; nt < 4; ++nt)
            bf[nt] = w2f[(tap * 4 + nt) * 64 + lane];
#pragma unroll
        for (int mt = 0; mt < 2; ++mt) {
            int oh2 = wv + mt * 8;
            int ih = 2 * oh2 + ky;
            if (ih < 32) {
                int iw = 2 * owl + kx;
                f16x8 af = *(const f16x8*)&c1s[(ih * 33 + iw) * 32 + cb];
#pragma unroll
                for (int nt = 0; nt < 4; ++nt)
                    acc2[mt][nt] = __builtin_amdgcn_mfma_f32_16x16x32_f16(
                        af, bf[nt], acc2[mt][nt], 0, 0, 0);
            }
        }
    }

#pragma unroll
    for (int nt = 0; nt < 4; ++nt) {
        float b = b2[nt * 16 + owl];
        float s = 0.f;
#pragma unroll
        for (int mt = 0; mt < 2; ++mt)
#pragma unroll
            for (int r = 0; r < 4; ++r)
                s += fmaxf(acc2[mt][nt][r] + b, 0.f);
        s += __shfl_xor(s, 16, 64);
        s += __shfl_xor(s, 32, 64);
        if (lane < 16) pl[wv * 64 + nt * 16 + lane] = s;
    }
    __syncthreads();
    if (tid < 64) {
        float s = 0.f;
#pragma unroll
        for (int w = 0; w < 8; ++w) s += pl[w * 64 + tid];
        pooled[n * 64 + tid] = s * (1.0f / 256.0f);
    }
}

// ---------------------------------------------------------------------------
// Dense: feats = relu(pooled @ dw + db);  xg = feats @ wx + b_gru.
// ---------------------------------------------------------------------------
__global__ __launch_bounds__(256) void k_dense(
    const float* __restrict__ pooled,  // [512][64]
    const float* __restrict__ dw,      // [64][256]
    const float* __restrict__ db,      // [256]
    const float* __restrict__ wx,      // [256][768]
    const float* __restrict__ bg,      // [768]
    float* __restrict__ xg)            // [512][768]
{
    __shared__ float ps[4 * 64];
    __shared__ float fs[4 * 256];
    const int tid = threadIdx.x;
    const int r0 = blockIdx.x * 4;

    ps[tid & 255] = pooled[r0 * 64 + (tid & 255)];
    __syncthreads();

    {
        float a0 = db[tid], a1 = a0, a2 = a0, a3 = a0;
        for (int k = 0; k < 64; ++k) {
            float w = dw[k * 256 + tid];
            a0 = fmaf(ps[0 * 64 + k], w, a0);
            a1 = fmaf(ps[1 * 64 + k], w, a1);
            a2 = fmaf(ps[2 * 64 + k], w, a2);
            a3 = fmaf(ps[3 * 64 + k], w, a3);
        }
        fs[0 * 256 + tid] = fmaxf(a0, 0.f);
        fs[1 * 256 + tid] = fmaxf(a1, 0.f);
        fs[2 * 256 + tid] = fmaxf(a2, 0.f);
        fs[3 * 256 + tid] = fmaxf(a3, 0.f);
    }
    __syncthreads();

    float acc[3][4];
#pragma unroll
    for (int g = 0; g < 3; ++g) {
        float b = bg[g * 256 + tid];
#pragma unroll
        for (int r = 0; r < 4; ++r) acc[g][r] = b;
    }
    for (int k = 0; k < 256; ++k) {
        float f0 = fs[0 * 256 + k], f1 = fs[1 * 256 + k];
        float f2 = fs[2 * 256 + k], f3 = fs[3 * 256 + k];
#pragma unroll
        for (int g = 0; g < 3; ++g) {
            float w = wx[k * 768 + g * 256 + tid];
            acc[g][0] = fmaf(f0, w, acc[g][0]);
            acc[g][1] = fmaf(f1, w, acc[g][1]);
            acc[g][2] = fmaf(f2, w, acc[g][2]);
            acc[g][3] = fmaf(f3, w, acc[g][3]);
        }
    }
#pragma unroll
    for (int r = 0; r < 4; ++r)
#pragma unroll
        for (int g = 0; g < 3; ++g)
            xg[(size_t)(r0 + r) * 768 + g * 256 + tid] = acc[g][r];
}

// ---------------------------------------------------------------------------
// GRU scan, 1024 threads (16 waves = 4 waves/SIMD — the allocator's proven
// 64-arch-VGPR operating point, R6).  Weight residency:
//   wz -> AGPRs a0..a31, wr -> a32..a63  (R12-proven mechanics, clobbered
//        reads so the allocator can never park values there)
//   wc -> LDS, padded 264 elem/col (528 B stride -> <=2-way = free)
// Arch demand ~40 < 64 -> no spills; unified 64+64 = 128/wave = exactly the
// 4-waves/SIMD budget.  Per-thread step ops ~half of R12 at 2x waves.
// col = wv*16 + (lane&15); kc = lane>>4 (k-chunk of 64).
// Reduction: shfl_xor 16 + 32.  2 barriers/step.
// ---------------------------------------------------------------------------
union H2I { h2_t h; int i; };

#define SV2(v, i) __builtin_shufflevector((v), (v), 2*(i), 2*(i)+1)

#define AWR(N, val) asm volatile("v_accvgpr_write_b32 a" #N ", %0" \
                                 :: "v"(val) : "a" #N)
#define ARD(N, dst) asm volatile("v_accvgpr_read_b32 %0, a" #N \
                                 : "=v"(dst) : : "a" #N)

#define AG4(P, BOFF, N0, N1, N2, N3) do {                               \
    union { f16x8 v; int i[4]; } u_;                                    \
    u_.v = *(const f16x8*)((P) + (BOFF));                               \
    AWR(N0, u_.i[0]); AWR(N1, u_.i[1]);                                 \
    AWR(N2, u_.i[2]); AWR(N3, u_.i[3]);                                 \
} while (0)

// phase1: one b128 of h (4 h2) -> 4 z-dots (a(Z..)) + 4 r-dots (a(R..))
#define ZR(J, Z0, Z1, Z2, Z3, R0, R1, R2, R3) do {                      \
    f16x8 hv_ = hh8[kc * 8 + J];                                        \
    h2_t h0_ = SV2(hv_, 0), h1_ = SV2(hv_, 1);                          \
    h2_t h2_ = SV2(hv_, 2), h3_ = SV2(hv_, 3);                          \
    H2I z0_, z1_, z2_, z3_, r0_, r1_, r2_, r3_;                         \
    ARD(Z0, z0_.i); ARD(Z1, z1_.i); ARD(Z2, z2_.i); ARD(Z3, z3_.i);     \
    ARD(R0, r0_.i); ARD(R1, r1_.i); ARD(R2, r2_.i); ARD(R3, r3_.i);     \
    az0 = fdot2(z0_.h, h0_, az0); az1 = fdot2(z1_.h, h1_, az1);         \
    az0 = fdot2(z2_.h, h2_, az0); az1 = fdot2(z3_.h, h3_, az1);         \
    ar0 = fdot2(r0_.h, h0_, ar0); ar1 = fdot2(r1_.h, h1_, ar1);         \
    ar0 = fdot2(r2_.h, h2_, ar0); ar1 = fdot2(r3_.h, h3_, ar1);         \
} while (0)

// phase2: c-dots from padded LDS (conflict-free)
#define CC(J) do {                                                      \
    f16x8 rv_ = rh8[kc * 8 + J];                                        \
    f16x8 wc_ = *(const f16x8*)(wcb + (J) * 8);                         \
    ah0 = fdot2(SV2(wc_, 0), SV2(rv_, 0), ah0);                         \
    ah1 = fdot2(SV2(wc_, 1), SV2(rv_, 1), ah1);                         \
    ah0 = fdot2(SV2(wc_, 2), SV2(rv_, 2), ah0);                         \
    ah1 = fdot2(SV2(wc_, 3), SV2(rv_, 3), ah1);                         \
} while (0)

__global__ __attribute__((amdgpu_flat_work_group_size(1024, 1024),
                          amdgpu_waves_per_eu(4, 4)))
void k_gru(
    const _Float16* __restrict__ whT,  // [768 cols][256 k] f16
    const float* __restrict__ xg,      // [512][768]
    float* __restrict__ out)           // [16*32*256] seq ++ [16*256] state
{
    __shared__ _Float16 wcs[256 * 264];  // candidate weights, padded, 132 KB
    __shared__ float hf[256];
    __shared__ _Float16 hh[256];
    __shared__ _Float16 rhh[256];

    const int b = blockIdx.x;
    const int tid = threadIdx.x;
    const int lane = tid & 63, wv = tid >> 6;
    const int col = wv * 16 + (lane & 15);
    const int kc = lane >> 4;          // 0..3
    const int k0 = kc * 64;

    // ---- wc -> LDS, linear chunks, 264-elem column stride ----
    for (int i = tid; i < 256 * 32; i += 1024) {
        int c  = i >> 5;               // col 0..255
        int cj = i & 31;               // 16B chunk
        *(f16x8*)&wcs[c * 264 + cj * 8] =
            *(const f16x8*)(whT + (size_t)(512 + c) * 256 + cj * 8);
    }

    // ---- wz -> a0..a31, wr -> a32..a63 (64 elems each, k0..k0+64) ----
    {
        const _Float16* pz = whT + (size_t)col * 256 + k0;
        AG4(pz,  0,  0,  1,  2,  3); AG4(pz,  8,  4,  5,  6,  7);
        AG4(pz, 16,  8,  9, 10, 11); AG4(pz, 24, 12, 13, 14, 15);
        AG4(pz, 32, 16, 17, 18, 19); AG4(pz, 40, 20, 21, 22, 23);
        AG4(pz, 48, 24, 25, 26, 27); AG4(pz, 56, 28, 29, 30, 31);
        const _Float16* pr = whT + (size_t)(col + 256) * 256 + k0;
        AG4(pr,  0, 32, 33, 34, 35); AG4(pr,  8, 36, 37, 38, 39);
        AG4(pr, 16, 40, 41, 42, 43); AG4(pr, 24, 44, 45, 46, 47);
        AG4(pr, 32, 48, 49, 50, 51); AG4(pr, 40, 52, 53, 54, 55);
        AG4(pr, 48, 56, 57, 58, 59); AG4(pr, 56, 60, 61, 62, 63);
    }

    if (tid < 256) { hf[tid] = 0.f; hh[tid] = (_Float16)0.f; }
    __syncthreads();

    const f16x8* hh8 = (const f16x8*)hh;    // 32 x 16B, broadcast reads
    const f16x8* rh8 = (const f16x8*)rhh;
    const _Float16* wcb = &wcs[col * 264 + kc * 64];
    float* outb = out + (size_t)b * 32 * 256;

    const float* xrow0 = xg + (size_t)(b * 32) * 768;
    float xz = xrow0[col], xr = xrow0[col + 256], xh = xrow0[col + 512];

    for (int t = 0; t < 32; ++t) {
        const int tn = (t < 31) ? t + 1 : 31;
        const float* xnext = xg + (size_t)(b * 32 + tn) * 768;
        float nxz = xnext[col], nxr = xnext[col + 256], nxh = xnext[col + 512];

        float az0 = 0.f, az1 = 0.f, ar0 = 0.f, ar1 = 0.f;
        ZR(0,  0,  1,  2,  3, 32, 33, 34, 35);
        ZR(1,  4,  5,  6,  7, 36, 37, 38, 39);
        ZR(2,  8,  9, 10, 11, 40, 41, 42, 43);
        ZR(3, 12, 13, 14, 15, 44, 45, 46, 47);
        ZR(4, 16, 17, 18, 19, 48, 49, 50, 51);
        ZR(5, 20, 21, 22, 23, 52, 53, 54, 55);
        ZR(6, 24, 25, 26, 27, 56, 57, 58, 59);
        ZR(7, 28, 29, 30, 31, 60, 61, 62, 63);

        float azs = az0 + az1;
        float ars = ar0 + ar1;
        azs += __shfl_xor(azs, 16, 64);
        azs += __shfl_xor(azs, 32, 64);
        ars += __shfl_xor(ars, 16, 64);
        ars += __shfl_xor(ars, 32, 64);
        float hold = hf[col];
        float z = 1.f / (1.f + __expf(-(azs + xz)));
        float r = 1.f / (1.f + __expf(-(ars + xr)));
        if (kc == 0) rhh[col] = (_Float16)(r * hold);
        __syncthreads();                          // B2: rhh visible

        float ah0 = 0.f, ah1 = 0.f;
        CC(0); CC(1); CC(2); CC(3);
        CC(4); CC(5); CC(6); CC(7);

        float ahs = ah0 + ah1;
        ahs += __shfl_xor(ahs, 16, 64);
        ahs += __shfl_xor(ahs, 32, 64);
        float sx = ahs + xh;
        sx = fminf(fmaxf(sx, -15.f), 15.f);
        float e2 = __expf(2.f * sx);
        float hc = (e2 - 1.f) / (e2 + 1.f);       // tanh
        float hn = z * hold + (1.f - z) * hc;

        if (kc == 0) {
            hf[col] = hn;
            hh[col] = (_Float16)hn;
            outb[t * 256 + col] = hn;
            if (t == 31) out[16 * 32 * 256 + b * 256 + col] = hn;
        }
        xz = nxz; xr = nxr; xh = nxh;
        __syncthreads();                          // B3: h(t) visible
    }
}

// ---------------------------------------------------------------------------
extern "C" void kernel_launch(void* const* d_in, const int* in_sizes, int n_in,
                              void* d_out, int out_size, void* d_ws,
                              size_t ws_size, hipStream_t stream)
{
    const float* x  = (const float*)d_in[0];
    const float* w1 = (const float*)d_in[1];
    const float* b1 = (const float*)d_in[2];
    const float* w2 = (const float*)d_in[3];
    const float* b2 = (const float*)d_in[4];
    const float* dw = (const float*)d_in[5];
    const float* db = (const float*)d_in[6];
    const float* wx = (const float*)d_in[7];
    const float* wh = (const float*)d_in[8];
    const float* bg = (const float*)d_in[9];
    float* out = (float*)d_out;

    float* pooled = (float*)d_ws;                  // 512*64 f32
    float* xg = pooled + 512 * 64;                 // 512*768 f32
    f16x8* w2f = (f16x8*)(xg + 512 * 768);         // 9*4*64 f16x8 (36.9 KB)
    _Float16* whT = (_Float16*)(w2f + 9 * 4 * 64); // 768*256 f16 (384 KB)

    k_prep<<<777, 256, 0, stream>>>(w2, w2f, wh, whT);
    k_conv<<<512, 512, 0, stream>>>(x, w1, b1, w2f, b2, pooled);
    k_dense<<<128, 256, 0, stream>>>(pooled, dw, db, wx, bg, xg);
    k_gru<<<16, 1024, 0, stream>>>(whT, xg, out);
}